// Round 12
// baseline (143.824 us; speedup 1.0000x reference)
//
#include <hip/hip_runtime.h>
#include <hip/hip_bf16.h>
#include <math.h>

#define BB 64
#define LL 2048
#define HH 512
#define EE 512
#define VV 32000
#define H3 1536
#define CH_ROWS 64
#define NCH 32  // LL / CH_ROWS

typedef __attribute__((ext_vector_type(8))) __bf16 bf16x8;
typedef __attribute__((ext_vector_type(4))) float f32x4;

__device__ __forceinline__ void ld8(const float* __restrict__ p, float* v) {
  float4 a = *(const float4*)p;
  float4 b = *(const float4*)(p + 4);
  v[0]=a.x; v[1]=a.y; v[2]=a.z; v[3]=a.w;
  v[4]=b.x; v[5]=b.y; v[6]=b.z; v[7]=b.w;
}
__device__ __forceinline__ void ld16(const float* __restrict__ p, float* v) {
  ld8(p, v); ld8(p + 8, v + 8);
}
__device__ __forceinline__ float wsum(float v) {
#pragma unroll
  for (int off = 32; off; off >>= 1) v += __shfl_xor(v, off);
  return v;
}
__device__ __forceinline__ unsigned short f2bf(float f) {
  unsigned int u = __float_as_uint(f);
  u = (u + 0x7FFFu + ((u >> 16) & 1u)) >> 16;
  return (unsigned short)u;
}

// ---------------- K1: GRU gates (R6-proven) -----------------------------
__device__ __forceinline__ void k1_proc(
    const float wih[2][8], const float whh[2][8], const float xv[8],
    const float hv[8], int b, int j0, int lane,
    const float* __restrict__ bih, const float* __restrict__ bhh,
    float* __restrict__ gi, float* __restrict__ gh) {
#pragma unroll
  for (int r = 0; r < 2; ++r) {
    float di = 0.f, dh = 0.f;
#pragma unroll
    for (int i = 0; i < 8; ++i) {
      di += wih[r][i] * xv[i];
      dh += whh[r][i] * hv[i];
    }
    di = wsum(di);
    dh = wsum(dh);
    if (lane == 0) {
      gi[b * H3 + j0 + r] = di + bih[j0 + r];
      gh[b * H3 + j0 + r] = dh + bhh[j0 + r];
    }
  }
}

__global__ __launch_bounds__(256) void k1_gates(
    const int* __restrict__ seq, const float* __restrict__ h,
    const float* __restrict__ emb, const float* __restrict__ Wih,
    const float* __restrict__ Whh, const float* __restrict__ bih,
    const float* __restrict__ bhh, float* __restrict__ gi,
    float* __restrict__ gh) {
  int lane = threadIdx.x & 63;
  int wid = blockIdx.x * 4 + (threadIdx.x >> 6);  // 0..1535
  int jp = wid >> 1, bh = wid & 1;
  int j0 = jp * 2;
  float wih[2][8], whh[2][8];
#pragma unroll
  for (int r = 0; r < 2; ++r) {
    ld8(Wih + (size_t)(j0 + r) * EE + lane * 8, wih[r]);
    ld8(Whh + (size_t)(j0 + r) * HH + lane * 8, whh[r]);
  }
  int bs = bh * 32;
  float xvA[8], hvA[8], xvB[8], hvB[8];
  ld8(emb + (size_t)seq[bs] * EE + lane * 8, xvA);
  ld8(h + bs * HH + lane * 8, hvA);
#pragma unroll
  for (int bi = 0; bi < 32; bi += 2) {
    int b = bs + bi;
    ld8(emb + (size_t)seq[b + 1] * EE + lane * 8, xvB);
    ld8(h + (b + 1) * HH + lane * 8, hvB);
    k1_proc(wih, whh, xvA, hvA, b, j0, lane, bih, bhh, gi, gh);
    if (bi + 2 < 32) {
      ld8(emb + (size_t)seq[b + 2] * EE + lane * 8, xvA);
      ld8(h + (b + 2) * HH + lane * 8, hvA);
    }
    k1_proc(wih, whh, xvB, hvB, b + 1, j0, lane, bih, bhh, gi, gh);
  }
}

// ---------------- K2: h_new + out1/out3 + cat[:, :512] (R4-proven) ------
__global__ __launch_bounds__(256) void k2_hnew(
    const float* __restrict__ gi, const float* __restrict__ gh,
    const float* __restrict__ h, const float* __restrict__ feed,
    float* __restrict__ cat, float* __restrict__ out1,
    float* __restrict__ out3) {
  int t = blockIdx.x * 256 + threadIdx.x;  // 32768
  int b = t >> 9, k = t & 511;
  const float* gib = gi + b * H3;
  const float* ghb = gh + b * H3;
  float r = 1.f / (1.f + __expf(-(gib[k] + ghb[k])));
  float z = 1.f / (1.f + __expf(-(gib[k + HH] + ghb[k + HH])));
  float n = tanhf(gib[k + 2 * HH] + r * ghb[k + 2 * HH]);
  float hn = (1.f - z) * n + z * h[t];
  cat[b * 1024 + k] = hn;
  out1[t] = hn;
  out3[t] = feed[t];
}

// ---------------- K3: persistent streaming attention --------------------
// 1024 blocks (4/CU), each processes 2 chunks of the SAME batch b:
// ch = (bid&15) and (bid&15)+16. Amortizes per-block startup (TLB warm-up /
// latency ramp) over 2 enc passes; hv loaded once. Per-chunk body = R11's
// proven 2-row ping-pong with LDS score stash.
__device__ __forceinline__ void k3row(const float ev[8], const float hv[8],
                                      int idx, int lane,
                                      float* __restrict__ sds,
                                      float& m, float& s, float c[8]) {
  float d = 0.f;
#pragma unroll
  for (int i = 0; i < 8; ++i) d += hv[i] * ev[i];
  d = wsum(d);
  if (lane == 0) sds[idx] = d;  // LDS (lgkmcnt), not global
  float mn = fmaxf(m, d);
  float sc = __expf(m - mn);  // 1.0 when max unchanged; 0 on first row
  float wq = __expf(d - mn);
  s = s * sc + wq;
#pragma unroll
  for (int i = 0; i < 8; ++i) c[i] = c[i] * sc + wq * ev[i];
  m = mn;
}

__global__ __launch_bounds__(256) void k3_attn(
    const float* __restrict__ enc, const float* __restrict__ cat,
    float* __restrict__ scores, float* __restrict__ pm,
    float* __restrict__ ps, float* __restrict__ pc) {
  int bid = blockIdx.x;  // 0..1023
  int b = bid >> 4;
  int ch0 = bid & 15;
  int w = threadIdx.x >> 6, lane = threadIdx.x & 63;
  int tid = threadIdx.x;
  int k0 = lane * 8;
  __shared__ float sds[CH_ROWS];
  __shared__ float sm[4], ssum[4];
  __shared__ float scx[4][512];

  float hv[8];
  ld8(cat + b * 1024 + k0, hv);

#pragma unroll
  for (int u = 0; u < 2; ++u) {
    int ch = ch0 + 16 * u;
    const float* eb = enc + ((size_t)b * LL + ch * CH_ROWS) * HH;
    float m = -INFINITY, s = 0.f, c[8];
#pragma unroll
    for (int i = 0; i < 8; ++i) c[i] = 0.f;

    float evA[8], evB[8];
    ld8(eb + (size_t)w * HH + k0, evA);
    ld8(eb + (size_t)(w + 4) * HH + k0, evB);
#pragma unroll
    for (int j = 0; j < 16; j += 2) {
      if (j + 2 < 16) {
        k3row(evA, hv, w + 4 * j, lane, sds, m, s, c);
        ld8(eb + (size_t)(w + 4 * (j + 2)) * HH + k0, evA);
      } else {
        k3row(evA, hv, w + 4 * j, lane, sds, m, s, c);
      }
      if (j + 3 < 16) {
        k3row(evB, hv, w + 4 * (j + 1), lane, sds, m, s, c);
        ld8(eb + (size_t)(w + 4 * (j + 3)) * HH + k0, evB);
      } else {
        k3row(evB, hv, w + 4 * (j + 1), lane, sds, m, s, c);
      }
    }

    if (lane == 0) { sm[w] = m; ssum[w] = s; }
#pragma unroll
    for (int i = 0; i < 8; ++i) scx[w][k0 + i] = c[i];
    __syncthreads();

    // flush scores (coalesced, once per chunk)
    if (tid < CH_ROWS) scores[b * LL + ch * CH_ROWS + tid] = sds[tid];

    float mb = fmaxf(fmaxf(sm[0], sm[1]), fmaxf(sm[2], sm[3]));
    if (tid == 0) {
      float sb = 0.f;
#pragma unroll
      for (int w2 = 0; w2 < 4; ++w2) sb += ssum[w2] * __expf(sm[w2] - mb);
      pm[b * NCH + ch] = mb;
      ps[b * NCH + ch] = sb;
    }
    for (int k = tid; k < 512; k += 256) {
      float v = 0.f;
#pragma unroll
      for (int w2 = 0; w2 < 4; ++w2)
        v += scx[w2][k] * __expf(sm[w2] - mb);
      pc[(size_t)(b * NCH + ch) * 512 + k] = v;
    }
    __syncthreads();  // LDS reuse guard for next chunk
  }
}

// ---------------- K45: combine -> ctx + attn-weights output -------------
__global__ __launch_bounds__(256) void k45_ctx(
    const float* __restrict__ pm, const float* __restrict__ ps,
    const float* __restrict__ pc, const float* __restrict__ scores,
    float* __restrict__ cat, float* __restrict__ out2) {
  int b = blockIdx.x;
  int tid = threadIdx.x;
  float mb = -INFINITY;
#pragma unroll
  for (int ch = 0; ch < NCH; ++ch) mb = fmaxf(mb, pm[b * NCH + ch]);
  float e[NCH];
  float den = 0.f;
#pragma unroll
  for (int ch = 0; ch < NCH; ++ch) {
    e[ch] = __expf(pm[b * NCH + ch] - mb);
    den += ps[b * NCH + ch] * e[ch];
  }
  for (int k = tid; k < 512; k += 256) {
    float v = 0.f;
#pragma unroll
    for (int ch = 0; ch < NCH; ++ch)
      v += pc[(size_t)(b * NCH + ch) * 512 + k] * e[ch];
    cat[b * 1024 + 512 + k] = v / den;
  }
  float inv = 1.f / den;
  for (int t = tid; t < LL; t += 256) {
    out2[b * LL + t] = __expf(scores[b * LL + t] - mb) * inv;
  }
}

// ---------------- K6: concat GEMV -> bf16 (256 blocks, x4 loop) ---------
__global__ __launch_bounds__(256) void k6_concat(
    const float* __restrict__ cat, const float* __restrict__ Wc,
    const float* __restrict__ bc, unsigned short* __restrict__ co_bf) {
  int lane = threadIdx.x & 63;
#pragma unroll
  for (int it = 0; it < 4; ++it) {
    int wid = it * 1024 + blockIdx.x * 4 + (threadIdx.x >> 6);  // 0..4095
    int k = wid >> 3, bg = wid & 7;
    float wv[16];
    ld16(Wc + (size_t)k * 1024 + lane * 16, wv);
    float bk = bc[k];
    for (int b = bg * 8; b < bg * 8 + 8; ++b) {
      float cv[16];
      ld16(cat + b * 1024 + lane * 16, cv);
      float d = 0.f;
#pragma unroll
      for (int i = 0; i < 16; ++i) d += wv[i] * cv[i];
      d = wsum(d);
      if (lane == 0) co_bf[b * HH + k] = f2bf(tanhf(d + bk));
    }
  }
}

// ---------------- K7: MFMA output GEMM (proven R4 form) -----------------
__global__ __launch_bounds__(256) void k7_out(
    const unsigned short* __restrict__ co_bf, const float* __restrict__ Wo,
    const float* __restrict__ bo, float* __restrict__ out0) {
  int t = threadIdx.x;
  int lane = t & 63, w = t >> 6;
  int v0 = blockIdx.x * 64 + w * 16;
  int l15 = lane & 15;
  int kbase = (lane >> 4) * 8;
  int vrow = v0 + l15;
  const float* wrow = Wo + (size_t)vrow * HH;

  f32x4 acc[4];
#pragma unroll
  for (int j = 0; j < 4; ++j) acc[j] = (f32x4){0.f, 0.f, 0.f, 0.f};

  for (int ks = 0; ks < HH; ks += 32) {
    int k = ks + kbase;
    float4 wa = *(const float4*)(wrow + k);
    float4 wb = *(const float4*)(wrow + k + 4);
    union { unsigned short u[8]; bf16x8 v; } B;
    B.u[0] = f2bf(wa.x); B.u[1] = f2bf(wa.y);
    B.u[2] = f2bf(wa.z); B.u[3] = f2bf(wa.w);
    B.u[4] = f2bf(wb.x); B.u[5] = f2bf(wb.y);
    B.u[6] = f2bf(wb.z); B.u[7] = f2bf(wb.w);
#pragma unroll
    for (int j = 0; j < 4; ++j) {
      bf16x8 A = *(const bf16x8*)(co_bf + (size_t)(j * 16 + l15) * HH + k);
      acc[j] = __builtin_amdgcn_mfma_f32_16x16x32_bf16(A, B.v, acc[j], 0, 0, 0);
    }
  }

  float bias = bo[vrow];
#pragma unroll
  for (int j = 0; j < 4; ++j) {
    int b0 = j * 16 + (lane >> 4) * 4;
#pragma unroll
    for (int r = 0; r < 4; ++r) {
      out0[(size_t)(b0 + r) * VV + vrow] = acc[j][r] + bias;
    }
  }
}

extern "C" void kernel_launch(void* const* d_in, const int* in_sizes, int n_in,
                              void* d_out, int out_size, void* d_ws,
                              size_t ws_size, hipStream_t stream) {
  const int* seq = (const int*)d_in[0];
  const float* last_hidden = (const float*)d_in[1];
  const float* enc = (const float*)d_in[2];
  // d_in[3] encoder_labels unused
  const float* feed = (const float*)d_in[4];
  const float* emb = (const float*)d_in[5];
  const float* Wih = (const float*)d_in[6];
  const float* Whh = (const float*)d_in[7];
  const float* bih = (const float*)d_in[8];
  const float* bhh = (const float*)d_in[9];
  const float* Wc = (const float*)d_in[10];
  const float* bc = (const float*)d_in[11];
  const float* Wo = (const float*)d_in[12];
  const float* bo = (const float*)d_in[13];

  float* out = (float*)d_out;
  float* out0 = out;            // B*V
  float* out1 = out + 2048000;  // B*H
  float* out2 = out + 2080768;  // B*L
  float* out3 = out + 2211840;  // B*H

  float* ws = (float*)d_ws;
  float* gi = ws;                  // 98304
  float* gh = gi + 98304;          // 98304
  float* cat = gh + 98304;         // 65536 (h_new | context)
  float* scores = cat + 65536;     // 131072
  float* pm = scores + 131072;     // 2048
  float* ps = pm + 2048;           // 2048
  float* pc = ps + 2048;           // 1048576 (B*NCH*512)
  unsigned short* co_bf = (unsigned short*)(pc + 1048576);  // 32768 u16

  hipLaunchKernelGGL(k1_gates, dim3(384), dim3(256), 0, stream,
                     seq, last_hidden, emb, Wih, Whh, bih, bhh, gi, gh);
  hipLaunchKernelGGL(k2_hnew, dim3(128), dim3(256), 0, stream,
                     gi, gh, last_hidden, feed, cat, out1, out3);
  hipLaunchKernelGGL(k3_attn, dim3(1024), dim3(256), 0, stream,
                     enc, cat, scores, pm, ps, pc);
  hipLaunchKernelGGL(k45_ctx, dim3(64), dim3(256), 0, stream,
                     pm, ps, pc, scores, cat, out2);
  hipLaunchKernelGGL(k6_concat, dim3(256), dim3(256), 0, stream,
                     cat, Wc, bc, co_bf);
  hipLaunchKernelGGL(k7_out, dim3(500), dim3(256), 0, stream,
                     co_bf, Wo, bo, out0);
}

// Round 13
// 136.359 us; speedup vs baseline: 1.0547x; 1.0547x over previous
//
#include <hip/hip_runtime.h>
#include <hip/hip_bf16.h>
#include <math.h>

#define BB 64
#define LL 2048
#define HH 512
#define EE 512
#define VV 32000
#define H3 1536
#define CH_ROWS 64
#define NCH 32  // LL / CH_ROWS

typedef __attribute__((ext_vector_type(8))) __bf16 bf16x8;
typedef __attribute__((ext_vector_type(4))) float f32x4;

__device__ __forceinline__ void ld8(const float* __restrict__ p, float* v) {
  float4 a = *(const float4*)p;
  float4 b = *(const float4*)(p + 4);
  v[0]=a.x; v[1]=a.y; v[2]=a.z; v[3]=a.w;
  v[4]=b.x; v[5]=b.y; v[6]=b.z; v[7]=b.w;
}
__device__ __forceinline__ void ld16(const float* __restrict__ p, float* v) {
  ld8(p, v); ld8(p + 8, v + 8);
}
__device__ __forceinline__ float wsum(float v) {
#pragma unroll
  for (int off = 32; off; off >>= 1) v += __shfl_xor(v, off);
  return v;
}
__device__ __forceinline__ unsigned short f2bf(float f) {
  unsigned int u = __float_as_uint(f);
  u = (u + 0x7FFFu + ((u >> 16) & 1u)) >> 16;
  return (unsigned short)u;
}

// ---------------- K1: GRU gates (R6-proven) -----------------------------
__device__ __forceinline__ void k1_proc(
    const float wih[2][8], const float whh[2][8], const float xv[8],
    const float hv[8], int b, int j0, int lane,
    const float* __restrict__ bih, const float* __restrict__ bhh,
    float* __restrict__ gi, float* __restrict__ gh) {
#pragma unroll
  for (int r = 0; r < 2; ++r) {
    float di = 0.f, dh = 0.f;
#pragma unroll
    for (int i = 0; i < 8; ++i) {
      di += wih[r][i] * xv[i];
      dh += whh[r][i] * hv[i];
    }
    di = wsum(di);
    dh = wsum(dh);
    if (lane == 0) {
      gi[b * H3 + j0 + r] = di + bih[j0 + r];
      gh[b * H3 + j0 + r] = dh + bhh[j0 + r];
    }
  }
}

__global__ __launch_bounds__(256) void k1_gates(
    const int* __restrict__ seq, const float* __restrict__ h,
    const float* __restrict__ emb, const float* __restrict__ Wih,
    const float* __restrict__ Whh, const float* __restrict__ bih,
    const float* __restrict__ bhh, float* __restrict__ gi,
    float* __restrict__ gh) {
  int lane = threadIdx.x & 63;
  int wid = blockIdx.x * 4 + (threadIdx.x >> 6);  // 0..1535
  int jp = wid >> 1, bh = wid & 1;
  int j0 = jp * 2;
  float wih[2][8], whh[2][8];
#pragma unroll
  for (int r = 0; r < 2; ++r) {
    ld8(Wih + (size_t)(j0 + r) * EE + lane * 8, wih[r]);
    ld8(Whh + (size_t)(j0 + r) * HH + lane * 8, whh[r]);
  }
  int bs = bh * 32;
  float xvA[8], hvA[8], xvB[8], hvB[8];
  ld8(emb + (size_t)seq[bs] * EE + lane * 8, xvA);
  ld8(h + bs * HH + lane * 8, hvA);
#pragma unroll
  for (int bi = 0; bi < 32; bi += 2) {
    int b = bs + bi;
    ld8(emb + (size_t)seq[b + 1] * EE + lane * 8, xvB);
    ld8(h + (b + 1) * HH + lane * 8, hvB);
    k1_proc(wih, whh, xvA, hvA, b, j0, lane, bih, bhh, gi, gh);
    if (bi + 2 < 32) {
      ld8(emb + (size_t)seq[b + 2] * EE + lane * 8, xvA);
      ld8(h + (b + 2) * HH + lane * 8, hvA);
    }
    k1_proc(wih, whh, xvB, hvB, b + 1, j0, lane, bih, bhh, gi, gh);
  }
}

// ---------------- K2: h_new + out1/out3 + cat[:, :512] (R4-proven) ------
__global__ __launch_bounds__(256) void k2_hnew(
    const float* __restrict__ gi, const float* __restrict__ gh,
    const float* __restrict__ h, const float* __restrict__ feed,
    float* __restrict__ cat, float* __restrict__ out1,
    float* __restrict__ out3) {
  int t = blockIdx.x * 256 + threadIdx.x;  // 32768
  int b = t >> 9, k = t & 511;
  const float* gib = gi + b * H3;
  const float* ghb = gh + b * H3;
  float r = 1.f / (1.f + __expf(-(gib[k] + ghb[k])));
  float z = 1.f / (1.f + __expf(-(gib[k + HH] + ghb[k + HH])));
  float n = tanhf(gib[k + 2 * HH] + r * ghb[k + 2 * HH]);
  float hn = (1.f - z) * n + z * h[t];
  cat[b * 1024 + k] = hn;
  out1[t] = hn;
  out3[t] = feed[t];
}

// ---------------- K3: streaming attention, XCD-contiguous swizzle -------
// 2048 blocks. wrk = (bid&7)*256 + bid>>3  ->  XCD x (bid%8==x) covers
// wrk in [x*256,(x+1)*256) = batches [x*8, x*8+8), all 32 chunks, in
// page-sequential order. Each XCD first-touches only ~1/8 of enc
// (33.5 MB, ~17 2MB pages) instead of all ~134 pages.
__device__ __forceinline__ void k3row(const float ev[8], const float hv[8],
                                      int idx, int lane,
                                      float* __restrict__ sds,
                                      float& m, float& s, float c[8]) {
  float d = 0.f;
#pragma unroll
  for (int i = 0; i < 8; ++i) d += hv[i] * ev[i];
  d = wsum(d);
  if (lane == 0) sds[idx] = d;  // LDS (lgkmcnt), not global
  float mn = fmaxf(m, d);
  float sc = __expf(m - mn);  // 1.0 when max unchanged; 0 on first row
  float wq = __expf(d - mn);
  s = s * sc + wq;
#pragma unroll
  for (int i = 0; i < 8; ++i) c[i] = c[i] * sc + wq * ev[i];
  m = mn;
}

__global__ __launch_bounds__(256) void k3_attn(
    const float* __restrict__ enc, const float* __restrict__ cat,
    float* __restrict__ scores, float* __restrict__ pm,
    float* __restrict__ ps, float* __restrict__ pc) {
  int bid = blockIdx.x;                   // 0..2047
  int wrk = (bid & 7) * 256 + (bid >> 3); // XCD-contiguous work id
  int b = wrk >> 5;                       // 0..63
  int ch = wrk & 31;                      // 0..31
  int w = threadIdx.x >> 6, lane = threadIdx.x & 63;
  int k0 = lane * 8;
  __shared__ float sds[CH_ROWS];
  __shared__ float sm[4], ssum[4];
  __shared__ float scx[4][512];

  float hv[8];
  ld8(cat + b * 1024 + k0, hv);

  const float* eb = enc + ((size_t)b * LL + ch * CH_ROWS) * HH;
  float m = -INFINITY, s = 0.f, c[8];
#pragma unroll
  for (int i = 0; i < 8; ++i) c[i] = 0.f;

  float evA[8], evB[8];
  ld8(eb + (size_t)w * HH + k0, evA);
  ld8(eb + (size_t)(w + 4) * HH + k0, evB);
#pragma unroll
  for (int j = 0; j < 16; j += 2) {
    if (j + 2 < 16) {
      k3row(evA, hv, w + 4 * j, lane, sds, m, s, c);
      ld8(eb + (size_t)(w + 4 * (j + 2)) * HH + k0, evA);
    } else {
      k3row(evA, hv, w + 4 * j, lane, sds, m, s, c);
    }
    if (j + 3 < 16) {
      k3row(evB, hv, w + 4 * (j + 1), lane, sds, m, s, c);
      ld8(eb + (size_t)(w + 4 * (j + 3)) * HH + k0, evB);
    } else {
      k3row(evB, hv, w + 4 * (j + 1), lane, sds, m, s, c);
    }
  }

  if (lane == 0) { sm[w] = m; ssum[w] = s; }
#pragma unroll
  for (int i = 0; i < 8; ++i) scx[w][k0 + i] = c[i];
  __syncthreads();

  int tid = threadIdx.x;
  // flush scores (coalesced, once)
  if (tid < CH_ROWS) scores[b * LL + ch * CH_ROWS + tid] = sds[tid];

  float mb = fmaxf(fmaxf(sm[0], sm[1]), fmaxf(sm[2], sm[3]));
  if (tid == 0) {
    float sb = 0.f;
#pragma unroll
    for (int w2 = 0; w2 < 4; ++w2) sb += ssum[w2] * __expf(sm[w2] - mb);
    pm[b * NCH + ch] = mb;
    ps[b * NCH + ch] = sb;
  }
  for (int k = tid; k < 512; k += 256) {
    float v = 0.f;
#pragma unroll
    for (int w2 = 0; w2 < 4; ++w2) v += scx[w2][k] * __expf(sm[w2] - mb);
    pc[(size_t)(b * NCH + ch) * 512 + k] = v;
  }
}

// ---------------- K45: combine -> ctx + attn-weights output -------------
__global__ __launch_bounds__(256) void k45_ctx(
    const float* __restrict__ pm, const float* __restrict__ ps,
    const float* __restrict__ pc, const float* __restrict__ scores,
    float* __restrict__ cat, float* __restrict__ out2) {
  int b = blockIdx.x;
  int tid = threadIdx.x;
  float mb = -INFINITY;
#pragma unroll
  for (int ch = 0; ch < NCH; ++ch) mb = fmaxf(mb, pm[b * NCH + ch]);
  float e[NCH];
  float den = 0.f;
#pragma unroll
  for (int ch = 0; ch < NCH; ++ch) {
    e[ch] = __expf(pm[b * NCH + ch] - mb);
    den += ps[b * NCH + ch] * e[ch];
  }
  for (int k = tid; k < 512; k += 256) {
    float v = 0.f;
#pragma unroll
    for (int ch = 0; ch < NCH; ++ch)
      v += pc[(size_t)(b * NCH + ch) * 512 + k] * e[ch];
    cat[b * 1024 + 512 + k] = v / den;
  }
  float inv = 1.f / den;
  for (int t = tid; t < LL; t += 256) {
    out2[b * LL + t] = __expf(scores[b * LL + t] - mb) * inv;
  }
}

// ---------------- K6: concat GEMV -> bf16 (R11-proven, 1024 blocks) -----
__global__ __launch_bounds__(256) void k6_concat(
    const float* __restrict__ cat, const float* __restrict__ Wc,
    const float* __restrict__ bc, unsigned short* __restrict__ co_bf) {
  int lane = threadIdx.x & 63;
  int wid = blockIdx.x * 4 + (threadIdx.x >> 6);  // 0..4095
  int k = wid >> 3, bg = wid & 7;
  float wv[16];
  ld16(Wc + (size_t)k * 1024 + lane * 16, wv);
  float bk = bc[k];
  for (int b = bg * 8; b < bg * 8 + 8; ++b) {
    float cv[16];
    ld16(cat + b * 1024 + lane * 16, cv);
    float d = 0.f;
#pragma unroll
    for (int i = 0; i < 16; ++i) d += wv[i] * cv[i];
    d = wsum(d);
    if (lane == 0) co_bf[b * HH + k] = f2bf(tanhf(d + bk));
  }
}

// ---------------- K7: MFMA output GEMM, XCD-contiguous swizzle ----------
// 512 blocks (12 idle). wrk = (bid&7)*64 + bid>>3; XCD x covers vocab
// rows [x*4000.. ] contiguously (~8 MB, ~4 pages each).
__global__ __launch_bounds__(256) void k7_out(
    const unsigned short* __restrict__ co_bf, const float* __restrict__ Wo,
    const float* __restrict__ bo, float* __restrict__ out0) {
  int bid = blockIdx.x;
  int wrk = (bid & 7) * 64 + (bid >> 3);
  if (wrk >= 500) return;
  int t = threadIdx.x;
  int lane = t & 63, w = t >> 6;
  int v0 = wrk * 64 + w * 16;
  int l15 = lane & 15;
  int kbase = (lane >> 4) * 8;
  int vrow = v0 + l15;
  const float* wrow = Wo + (size_t)vrow * HH;

  f32x4 acc[4];
#pragma unroll
  for (int j = 0; j < 4; ++j) acc[j] = (f32x4){0.f, 0.f, 0.f, 0.f};

  for (int ks = 0; ks < HH; ks += 32) {
    int k = ks + kbase;
    float4 wa = *(const float4*)(wrow + k);
    float4 wb = *(const float4*)(wrow + k + 4);
    union { unsigned short u[8]; bf16x8 v; } B;
    B.u[0] = f2bf(wa.x); B.u[1] = f2bf(wa.y);
    B.u[2] = f2bf(wa.z); B.u[3] = f2bf(wa.w);
    B.u[4] = f2bf(wb.x); B.u[5] = f2bf(wb.y);
    B.u[6] = f2bf(wb.z); B.u[7] = f2bf(wb.w);
#pragma unroll
    for (int j = 0; j < 4; ++j) {
      bf16x8 A = *(const bf16x8*)(co_bf + (size_t)(j * 16 + l15) * HH + k);
      acc[j] = __builtin_amdgcn_mfma_f32_16x16x32_bf16(A, B.v, acc[j], 0, 0, 0);
    }
  }

  float bias = bo[vrow];
#pragma unroll
  for (int j = 0; j < 4; ++j) {
    int b0 = j * 16 + (lane >> 4) * 4;
#pragma unroll
    for (int r = 0; r < 4; ++r) {
      out0[(size_t)(b0 + r) * VV + vrow] = acc[j][r] + bias;
    }
  }
}

extern "C" void kernel_launch(void* const* d_in, const int* in_sizes, int n_in,
                              void* d_out, int out_size, void* d_ws,
                              size_t ws_size, hipStream_t stream) {
  const int* seq = (const int*)d_in[0];
  const float* last_hidden = (const float*)d_in[1];
  const float* enc = (const float*)d_in[2];
  // d_in[3] encoder_labels unused
  const float* feed = (const float*)d_in[4];
  const float* emb = (const float*)d_in[5];
  const float* Wih = (const float*)d_in[6];
  const float* Whh = (const float*)d_in[7];
  const float* bih = (const float*)d_in[8];
  const float* bhh = (const float*)d_in[9];
  const float* Wc = (const float*)d_in[10];
  const float* bc = (const float*)d_in[11];
  const float* Wo = (const float*)d_in[12];
  const float* bo = (const float*)d_in[13];

  float* out = (float*)d_out;
  float* out0 = out;            // B*V
  float* out1 = out + 2048000;  // B*H
  float* out2 = out + 2080768;  // B*L
  float* out3 = out + 2211840;  // B*H

  float* ws = (float*)d_ws;
  float* gi = ws;                  // 98304
  float* gh = gi + 98304;          // 98304
  float* cat = gh + 98304;         // 65536 (h_new | context)
  float* scores = cat + 65536;     // 131072
  float* pm = scores + 131072;     // 2048
  float* ps = pm + 2048;           // 2048
  float* pc = ps + 2048;           // 1048576 (B*NCH*512)
  unsigned short* co_bf = (unsigned short*)(pc + 1048576);  // 32768 u16

  hipLaunchKernelGGL(k1_gates, dim3(384), dim3(256), 0, stream,
                     seq, last_hidden, emb, Wih, Whh, bih, bhh, gi, gh);
  hipLaunchKernelGGL(k2_hnew, dim3(128), dim3(256), 0, stream,
                     gi, gh, last_hidden, feed, cat, out1, out3);
  hipLaunchKernelGGL(k3_attn, dim3(2048), dim3(256), 0, stream,
                     enc, cat, scores, pm, ps, pc);
  hipLaunchKernelGGL(k45_ctx, dim3(64), dim3(256), 0, stream,
                     pm, ps, pc, scores, cat, out2);
  hipLaunchKernelGGL(k6_concat, dim3(1024), dim3(256), 0, stream,
                     cat, Wc, bc, co_bf);
  hipLaunchKernelGGL(k7_out, dim3(512), dim3(256), 0, stream,
                     co_bf, Wo, bo, out0);
}

// Round 14
// 132.519 us; speedup vs baseline: 1.0853x; 1.0290x over previous
//
#include <hip/hip_runtime.h>
#include <hip/hip_bf16.h>
#include <math.h>

#define BB 64
#define LL 2048
#define HH 512
#define EE 512
#define VV 32000
#define H3 1536
#define CH_ROWS 64
#define NCH 32  // LL / CH_ROWS

typedef __attribute__((ext_vector_type(8))) __bf16 bf16x8;
typedef __attribute__((ext_vector_type(4))) float f32x4;

__device__ __forceinline__ void ld8(const float* __restrict__ p, float* v) {
  float4 a = *(const float4*)p;
  float4 b = *(const float4*)(p + 4);
  v[0]=a.x; v[1]=a.y; v[2]=a.z; v[3]=a.w;
  v[4]=b.x; v[5]=b.y; v[6]=b.z; v[7]=b.w;
}
__device__ __forceinline__ void ld16(const float* __restrict__ p, float* v) {
  ld8(p, v); ld8(p + 8, v + 8);
}
__device__ __forceinline__ float wsum(float v) {
#pragma unroll
  for (int off = 32; off; off >>= 1) v += __shfl_xor(v, off);
  return v;
}
__device__ __forceinline__ unsigned short f2bf(float f) {
  unsigned int u = __float_as_uint(f);
  u = (u + 0x7FFFu + ((u >> 16) & 1u)) >> 16;
  return (unsigned short)u;
}

// ---------------- K1: GRU gates (R6-proven) -----------------------------
__device__ __forceinline__ void k1_proc(
    const float wih[2][8], const float whh[2][8], const float xv[8],
    const float hv[8], int b, int j0, int lane,
    const float* __restrict__ bih, const float* __restrict__ bhh,
    float* __restrict__ gi, float* __restrict__ gh) {
#pragma unroll
  for (int r = 0; r < 2; ++r) {
    float di = 0.f, dh = 0.f;
#pragma unroll
    for (int i = 0; i < 8; ++i) {
      di += wih[r][i] * xv[i];
      dh += whh[r][i] * hv[i];
    }
    di = wsum(di);
    dh = wsum(dh);
    if (lane == 0) {
      gi[b * H3 + j0 + r] = di + bih[j0 + r];
      gh[b * H3 + j0 + r] = dh + bhh[j0 + r];
    }
  }
}

__global__ __launch_bounds__(256) void k1_gates(
    const int* __restrict__ seq, const float* __restrict__ h,
    const float* __restrict__ emb, const float* __restrict__ Wih,
    const float* __restrict__ Whh, const float* __restrict__ bih,
    const float* __restrict__ bhh, float* __restrict__ gi,
    float* __restrict__ gh) {
  int lane = threadIdx.x & 63;
  int wid = blockIdx.x * 4 + (threadIdx.x >> 6);  // 0..1535
  int jp = wid >> 1, bh = wid & 1;
  int j0 = jp * 2;
  float wih[2][8], whh[2][8];
#pragma unroll
  for (int r = 0; r < 2; ++r) {
    ld8(Wih + (size_t)(j0 + r) * EE + lane * 8, wih[r]);
    ld8(Whh + (size_t)(j0 + r) * HH + lane * 8, whh[r]);
  }
  int bs = bh * 32;
  float xvA[8], hvA[8], xvB[8], hvB[8];
  ld8(emb + (size_t)seq[bs] * EE + lane * 8, xvA);
  ld8(h + bs * HH + lane * 8, hvA);
#pragma unroll
  for (int bi = 0; bi < 32; bi += 2) {
    int b = bs + bi;
    ld8(emb + (size_t)seq[b + 1] * EE + lane * 8, xvB);
    ld8(h + (b + 1) * HH + lane * 8, hvB);
    k1_proc(wih, whh, xvA, hvA, b, j0, lane, bih, bhh, gi, gh);
    if (bi + 2 < 32) {
      ld8(emb + (size_t)seq[b + 2] * EE + lane * 8, xvA);
      ld8(h + (b + 2) * HH + lane * 8, hvA);
    }
    k1_proc(wih, whh, xvB, hvB, b + 1, j0, lane, bih, bhh, gi, gh);
  }
}

// ---------------- K2: h_new + out1/out3 + cat[:, :512] (R4-proven) ------
__global__ __launch_bounds__(256) void k2_hnew(
    const float* __restrict__ gi, const float* __restrict__ gh,
    const float* __restrict__ h, const float* __restrict__ feed,
    float* __restrict__ cat, float* __restrict__ out1,
    float* __restrict__ out3) {
  int t = blockIdx.x * 256 + threadIdx.x;  // 32768
  int b = t >> 9, k = t & 511;
  const float* gib = gi + b * H3;
  const float* ghb = gh + b * H3;
  float r = 1.f / (1.f + __expf(-(gib[k] + ghb[k])));
  float z = 1.f / (1.f + __expf(-(gib[k + HH] + ghb[k + HH])));
  float n = tanhf(gib[k + 2 * HH] + r * ghb[k + 2 * HH]);
  float hn = (1.f - z) * n + z * h[t];
  cat[b * 1024 + k] = hn;
  out1[t] = hn;
  out3[t] = feed[t];
}

// ---------------- K3 v5: wave-contiguous streaming attention ------------
// Lane L owns k-slices [4L,4L+4) and [256+4L,256+4L+4). Each row read =
// 2 VMEM instrs, each covering a CONTIGUOUS 1 KB (8 full cache lines, no
// holes) -- halves L2/fabric request count vs the lane*8 (32B-stride)
// layout used in R7-R13 (which never exceeded ~40% HBM peak).
__global__ __launch_bounds__(256) void k3_attn(
    const float* __restrict__ enc, const float* __restrict__ cat,
    float* __restrict__ scores, float* __restrict__ pm,
    float* __restrict__ ps, float* __restrict__ pc) {
  int b = blockIdx.y, ch = blockIdx.x;
  int w = threadIdx.x >> 6, lane = threadIdx.x & 63;
  int tid = threadIdx.x;
  int kq = 4 * lane;  // lane's k-offset
  __shared__ float sds[CH_ROWS];
  __shared__ float sm[4], ssum[4];
  __shared__ float scx[4][512];

  float4 h4a = *(const float4*)(cat + b * 1024 + kq);
  float4 h4b = *(const float4*)(cat + b * 1024 + 256 + kq);

  const float* eb = enc + ((size_t)b * LL + ch * CH_ROWS) * HH;
  float m = -INFINITY, s = 0.f;
  float4 ca = {0.f, 0.f, 0.f, 0.f}, cb = {0.f, 0.f, 0.f, 0.f};

  // 2-row ping-pong; wave w handles rows w+4j, j=0..15
  float4 eaA, e2A, eaB, e2B;
  {
    const float* r0 = eb + (size_t)w * HH;
    const float* r1 = eb + (size_t)(w + 4) * HH;
    eaA = *(const float4*)(r0 + kq);
    e2A = *(const float4*)(r0 + 256 + kq);
    eaB = *(const float4*)(r1 + kq);
    e2B = *(const float4*)(r1 + 256 + kq);
  }
#pragma unroll
  for (int j = 0; j < 16; j += 2) {
    // process A (row w+4j)
    {
      float d = eaA.x * h4a.x + eaA.y * h4a.y + eaA.z * h4a.z +
                eaA.w * h4a.w + e2A.x * h4b.x + e2A.y * h4b.y +
                e2A.z * h4b.z + e2A.w * h4b.w;
      d = wsum(d);
      if (lane == 0) sds[w + 4 * j] = d;
      float mn = fmaxf(m, d);
      float sc = __expf(m - mn);
      float wq = __expf(d - mn);
      s = s * sc + wq;
      ca.x = ca.x * sc + wq * eaA.x; ca.y = ca.y * sc + wq * eaA.y;
      ca.z = ca.z * sc + wq * eaA.z; ca.w = ca.w * sc + wq * eaA.w;
      cb.x = cb.x * sc + wq * e2A.x; cb.y = cb.y * sc + wq * e2A.y;
      cb.z = cb.z * sc + wq * e2A.z; cb.w = cb.w * sc + wq * e2A.w;
      m = mn;
    }
    if (j + 2 < 16) {
      const float* rn = eb + (size_t)(w + 4 * (j + 2)) * HH;
      eaA = *(const float4*)(rn + kq);
      e2A = *(const float4*)(rn + 256 + kq);
    }
    // process B (row w+4(j+1))
    {
      float d = eaB.x * h4a.x + eaB.y * h4a.y + eaB.z * h4a.z +
                eaB.w * h4a.w + e2B.x * h4b.x + e2B.y * h4b.y +
                e2B.z * h4b.z + e2B.w * h4b.w;
      d = wsum(d);
      if (lane == 0) sds[w + 4 * (j + 1)] = d;
      float mn = fmaxf(m, d);
      float sc = __expf(m - mn);
      float wq = __expf(d - mn);
      s = s * sc + wq;
      ca.x = ca.x * sc + wq * eaB.x; ca.y = ca.y * sc + wq * eaB.y;
      ca.z = ca.z * sc + wq * eaB.z; ca.w = ca.w * sc + wq * eaB.w;
      cb.x = cb.x * sc + wq * e2B.x; cb.y = cb.y * sc + wq * e2B.y;
      cb.z = cb.z * sc + wq * e2B.z; cb.w = cb.w * sc + wq * e2B.w;
      m = mn;
    }
    if (j + 3 < 16) {
      const float* rn = eb + (size_t)(w + 4 * (j + 3)) * HH;
      eaB = *(const float4*)(rn + kq);
      e2B = *(const float4*)(rn + 256 + kq);
    }
  }

  if (lane == 0) { sm[w] = m; ssum[w] = s; }
  ((float4*)(scx[w] + 0))[lane] = ca;
  ((float4*)(scx[w] + 256))[lane] = cb;
  __syncthreads();

  // flush scores (coalesced, once)
  if (tid < CH_ROWS) scores[b * LL + ch * CH_ROWS + tid] = sds[tid];

  float mb = fmaxf(fmaxf(sm[0], sm[1]), fmaxf(sm[2], sm[3]));
  if (tid == 0) {
    float sb = 0.f;
#pragma unroll
    for (int w2 = 0; w2 < 4; ++w2) sb += ssum[w2] * __expf(sm[w2] - mb);
    pm[b * NCH + ch] = mb;
    ps[b * NCH + ch] = sb;
  }
  for (int k = tid; k < 512; k += 256) {
    float v = 0.f;
#pragma unroll
    for (int w2 = 0; w2 < 4; ++w2) v += scx[w2][k] * __expf(sm[w2] - mb);
    pc[(size_t)(b * NCH + ch) * 512 + k] = v;
  }
}

// ---------------- K45: combine -> ctx + attn-weights output -------------
__global__ __launch_bounds__(256) void k45_ctx(
    const float* __restrict__ pm, const float* __restrict__ ps,
    const float* __restrict__ pc, const float* __restrict__ scores,
    float* __restrict__ cat, float* __restrict__ out2) {
  int b = blockIdx.x;
  int tid = threadIdx.x;
  float mb = -INFINITY;
#pragma unroll
  for (int ch = 0; ch < NCH; ++ch) mb = fmaxf(mb, pm[b * NCH + ch]);
  float e[NCH];
  float den = 0.f;
#pragma unroll
  for (int ch = 0; ch < NCH; ++ch) {
    e[ch] = __expf(pm[b * NCH + ch] - mb);
    den += ps[b * NCH + ch] * e[ch];
  }
  for (int k = tid; k < 512; k += 256) {
    float v = 0.f;
#pragma unroll
    for (int ch = 0; ch < NCH; ++ch)
      v += pc[(size_t)(b * NCH + ch) * 512 + k] * e[ch];
    cat[b * 1024 + 512 + k] = v / den;
  }
  float inv = 1.f / den;
  for (int t = tid; t < LL; t += 256) {
    out2[b * LL + t] = __expf(scores[b * LL + t] - mb) * inv;
  }
}

// ---------------- K6: concat GEMV -> bf16 (R11-proven) ------------------
__global__ __launch_bounds__(256) void k6_concat(
    const float* __restrict__ cat, const float* __restrict__ Wc,
    const float* __restrict__ bc, unsigned short* __restrict__ co_bf) {
  int lane = threadIdx.x & 63;
  int wid = blockIdx.x * 4 + (threadIdx.x >> 6);  // 0..4095
  int k = wid >> 3, bg = wid & 7;
  float wv[16];
  ld16(Wc + (size_t)k * 1024 + lane * 16, wv);
  float bk = bc[k];
  for (int b = bg * 8; b < bg * 8 + 8; ++b) {
    float cv[16];
    ld16(cat + b * 1024 + lane * 16, cv);
    float d = 0.f;
#pragma unroll
    for (int i = 0; i < 16; ++i) d += wv[i] * cv[i];
    d = wsum(d);
    if (lane == 0) co_bf[b * HH + k] = f2bf(tanhf(d + bk));
  }
}

// ---------------- K7: MFMA output GEMM (proven R4 form) -----------------
__global__ __launch_bounds__(256) void k7_out(
    const unsigned short* __restrict__ co_bf, const float* __restrict__ Wo,
    const float* __restrict__ bo, float* __restrict__ out0) {
  int t = threadIdx.x;
  int lane = t & 63, w = t >> 6;
  int v0 = blockIdx.x * 64 + w * 16;
  int l15 = lane & 15;
  int kbase = (lane >> 4) * 8;
  int vrow = v0 + l15;
  const float* wrow = Wo + (size_t)vrow * HH;

  f32x4 acc[4];
#pragma unroll
  for (int j = 0; j < 4; ++j) acc[j] = (f32x4){0.f, 0.f, 0.f, 0.f};

  for (int ks = 0; ks < HH; ks += 32) {
    int k = ks + kbase;
    float4 wa = *(const float4*)(wrow + k);
    float4 wb = *(const float4*)(wrow + k + 4);
    union { unsigned short u[8]; bf16x8 v; } B;
    B.u[0] = f2bf(wa.x); B.u[1] = f2bf(wa.y);
    B.u[2] = f2bf(wa.z); B.u[3] = f2bf(wa.w);
    B.u[4] = f2bf(wb.x); B.u[5] = f2bf(wb.y);
    B.u[6] = f2bf(wb.z); B.u[7] = f2bf(wb.w);
#pragma unroll
    for (int j = 0; j < 4; ++j) {
      bf16x8 A = *(const bf16x8*)(co_bf + (size_t)(j * 16 + l15) * HH + k);
      acc[j] = __builtin_amdgcn_mfma_f32_16x16x32_bf16(A, B.v, acc[j], 0, 0, 0);
    }
  }

  float bias = bo[vrow];
#pragma unroll
  for (int j = 0; j < 4; ++j) {
    int b0 = j * 16 + (lane >> 4) * 4;
#pragma unroll
    for (int r = 0; r < 4; ++r) {
      out0[(size_t)(b0 + r) * VV + vrow] = acc[j][r] + bias;
    }
  }
}

extern "C" void kernel_launch(void* const* d_in, const int* in_sizes, int n_in,
                              void* d_out, int out_size, void* d_ws,
                              size_t ws_size, hipStream_t stream) {
  const int* seq = (const int*)d_in[0];
  const float* last_hidden = (const float*)d_in[1];
  const float* enc = (const float*)d_in[2];
  // d_in[3] encoder_labels unused
  const float* feed = (const float*)d_in[4];
  const float* emb = (const float*)d_in[5];
  const float* Wih = (const float*)d_in[6];
  const float* Whh = (const float*)d_in[7];
  const float* bih = (const float*)d_in[8];
  const float* bhh = (const float*)d_in[9];
  const float* Wc = (const float*)d_in[10];
  const float* bc = (const float*)d_in[11];
  const float* Wo = (const float*)d_in[12];
  const float* bo = (const float*)d_in[13];

  float* out = (float*)d_out;
  float* out0 = out;            // B*V
  float* out1 = out + 2048000;  // B*H
  float* out2 = out + 2080768;  // B*L
  float* out3 = out + 2211840;  // B*H

  float* ws = (float*)d_ws;
  float* gi = ws;                  // 98304
  float* gh = gi + 98304;          // 98304
  float* cat = gh + 98304;         // 65536 (h_new | context)
  float* scores = cat + 65536;     // 131072
  float* pm = scores + 131072;     // 2048
  float* ps = pm + 2048;           // 2048
  float* pc = ps + 2048;           // 1048576 (B*NCH*512)
  unsigned short* co_bf = (unsigned short*)(pc + 1048576);  // 32768 u16

  hipLaunchKernelGGL(k1_gates, dim3(384), dim3(256), 0, stream,
                     seq, last_hidden, emb, Wih, Whh, bih, bhh, gi, gh);
  hipLaunchKernelGGL(k2_hnew, dim3(128), dim3(256), 0, stream,
                     gi, gh, last_hidden, feed, cat, out1, out3);
  hipLaunchKernelGGL(k3_attn, dim3(NCH, BB), dim3(256), 0, stream,
                     enc, cat, scores, pm, ps, pc);
  hipLaunchKernelGGL(k45_ctx, dim3(64), dim3(256), 0, stream,
                     pm, ps, pc, scores, cat, out2);
  hipLaunchKernelGGL(k6_concat, dim3(1024), dim3(256), 0, stream,
                     cat, Wc, bc, co_bf);
  hipLaunchKernelGGL(k7_out, dim3(500), dim3(256), 0, stream,
                     co_bf, Wo, bo, out0);
}

// Round 16
// 125.677 us; speedup vs baseline: 1.1444x; 1.0544x over previous
//
#include <hip/hip_runtime.h>
#include <hip/hip_bf16.h>
#include <math.h>

#define BB 64
#define LL 2048
#define HH 512
#define EE 512
#define VV 32000
#define H3 1536
#define CH_ROWS 64
#define NCH 32  // LL / CH_ROWS

typedef __attribute__((ext_vector_type(8))) __bf16 bf16x8;
typedef __attribute__((ext_vector_type(4))) float f32x4;

__device__ __forceinline__ void ld8(const float* __restrict__ p, float* v) {
  float4 a = *(const float4*)p;
  float4 b = *(const float4*)(p + 4);
  v[0]=a.x; v[1]=a.y; v[2]=a.z; v[3]=a.w;
  v[4]=b.x; v[5]=b.y; v[6]=b.z; v[7]=b.w;
}
__device__ __forceinline__ void ld16(const float* __restrict__ p, float* v) {
  ld8(p, v); ld8(p + 8, v + 8);
}
// nontemporal float4 load via native clang vector (builtin rejects
// HIP_vector_type structs)
__device__ __forceinline__ f32x4 ldnt4(const float* __restrict__ p) {
  return __builtin_nontemporal_load((const f32x4*)p);
}
__device__ __forceinline__ float wsum(float v) {
#pragma unroll
  for (int off = 32; off; off >>= 1) v += __shfl_xor(v, off);
  return v;
}
__device__ __forceinline__ unsigned short f2bf(float f) {
  unsigned int u = __float_as_uint(f);
  u = (u + 0x7FFFu + ((u >> 16) & 1u)) >> 16;
  return (unsigned short)u;
}

// ---------------- K1: GRU gates (R6-proven) -----------------------------
__device__ __forceinline__ void k1_proc(
    const float wih[2][8], const float whh[2][8], const float xv[8],
    const float hv[8], int b, int j0, int lane,
    const float* __restrict__ bih, const float* __restrict__ bhh,
    float* __restrict__ gi, float* __restrict__ gh) {
#pragma unroll
  for (int r = 0; r < 2; ++r) {
    float di = 0.f, dh = 0.f;
#pragma unroll
    for (int i = 0; i < 8; ++i) {
      di += wih[r][i] * xv[i];
      dh += whh[r][i] * hv[i];
    }
    di = wsum(di);
    dh = wsum(dh);
    if (lane == 0) {
      gi[b * H3 + j0 + r] = di + bih[j0 + r];
      gh[b * H3 + j0 + r] = dh + bhh[j0 + r];
    }
  }
}

__global__ __launch_bounds__(256) void k1_gates(
    const int* __restrict__ seq, const float* __restrict__ h,
    const float* __restrict__ emb, const float* __restrict__ Wih,
    const float* __restrict__ Whh, const float* __restrict__ bih,
    const float* __restrict__ bhh, float* __restrict__ gi,
    float* __restrict__ gh) {
  int lane = threadIdx.x & 63;
  int wid = blockIdx.x * 4 + (threadIdx.x >> 6);  // 0..1535
  int jp = wid >> 1, bh = wid & 1;
  int j0 = jp * 2;
  float wih[2][8], whh[2][8];
#pragma unroll
  for (int r = 0; r < 2; ++r) {
    ld8(Wih + (size_t)(j0 + r) * EE + lane * 8, wih[r]);
    ld8(Whh + (size_t)(j0 + r) * HH + lane * 8, whh[r]);
  }
  int bs = bh * 32;
  float xvA[8], hvA[8], xvB[8], hvB[8];
  ld8(emb + (size_t)seq[bs] * EE + lane * 8, xvA);
  ld8(h + bs * HH + lane * 8, hvA);
#pragma unroll
  for (int bi = 0; bi < 32; bi += 2) {
    int b = bs + bi;
    ld8(emb + (size_t)seq[b + 1] * EE + lane * 8, xvB);
    ld8(h + (b + 1) * HH + lane * 8, hvB);
    k1_proc(wih, whh, xvA, hvA, b, j0, lane, bih, bhh, gi, gh);
    if (bi + 2 < 32) {
      ld8(emb + (size_t)seq[b + 2] * EE + lane * 8, xvA);
      ld8(h + (b + 2) * HH + lane * 8, hvA);
    }
    k1_proc(wih, whh, xvB, hvB, b + 1, j0, lane, bih, bhh, gi, gh);
  }
}

// ---------------- K2: h_new + out1/out3 + cat[:, :512] (R4-proven) ------
__global__ __launch_bounds__(256) void k2_hnew(
    const float* __restrict__ gi, const float* __restrict__ gh,
    const float* __restrict__ h, const float* __restrict__ feed,
    float* __restrict__ cat, float* __restrict__ out1,
    float* __restrict__ out3) {
  int t = blockIdx.x * 256 + threadIdx.x;  // 32768
  int b = t >> 9, k = t & 511;
  const float* gib = gi + b * H3;
  const float* ghb = gh + b * H3;
  float r = 1.f / (1.f + __expf(-(gib[k] + ghb[k])));
  float z = 1.f / (1.f + __expf(-(gib[k + HH] + ghb[k + HH])));
  float n = tanhf(gib[k + 2 * HH] + r * ghb[k + 2 * HH]);
  float hn = (1.f - z) * n + z * h[t];
  cat[b * 1024 + k] = hn;
  out1[t] = hn;
  out3[t] = feed[t];
}

// ---------------- K3 v6: wave-contiguous + NONTEMPORAL enc loads --------
// enc has ZERO reuse (each element read once by one block) -> nt loads
// bypass cache allocation. Testing the hypothesis that first-touch reads
// are cache-allocation-BW-limited (~2.5 TB/s observed, vs 6.7 TB/s warm).
__global__ __launch_bounds__(256) void k3_attn(
    const float* __restrict__ enc, const float* __restrict__ cat,
    float* __restrict__ scores, float* __restrict__ pm,
    float* __restrict__ ps, float* __restrict__ pc) {
  int b = blockIdx.y, ch = blockIdx.x;
  int w = threadIdx.x >> 6, lane = threadIdx.x & 63;
  int tid = threadIdx.x;
  int kq = 4 * lane;  // lane's k-offset
  __shared__ float sds[CH_ROWS];
  __shared__ float sm[4], ssum[4];
  __shared__ float scx[4][512];

  f32x4 h4a = *(const f32x4*)(cat + b * 1024 + kq);
  f32x4 h4b = *(const f32x4*)(cat + b * 1024 + 256 + kq);

  const float* eb = enc + ((size_t)b * LL + ch * CH_ROWS) * HH;
  float m = -INFINITY, s = 0.f;
  f32x4 ca = {0.f, 0.f, 0.f, 0.f}, cb = {0.f, 0.f, 0.f, 0.f};

  // 2-row ping-pong; wave w handles rows w+4j, j=0..15
  f32x4 eaA, e2A, eaB, e2B;
  {
    const float* r0 = eb + (size_t)w * HH;
    const float* r1 = eb + (size_t)(w + 4) * HH;
    eaA = ldnt4(r0 + kq);
    e2A = ldnt4(r0 + 256 + kq);
    eaB = ldnt4(r1 + kq);
    e2B = ldnt4(r1 + 256 + kq);
  }
#pragma unroll
  for (int j = 0; j < 16; j += 2) {
    // process A (row w+4j)
    {
      float d = eaA.x * h4a.x + eaA.y * h4a.y + eaA.z * h4a.z +
                eaA.w * h4a.w + e2A.x * h4b.x + e2A.y * h4b.y +
                e2A.z * h4b.z + e2A.w * h4b.w;
      d = wsum(d);
      if (lane == 0) sds[w + 4 * j] = d;
      float mn = fmaxf(m, d);
      float sc = __expf(m - mn);
      float wq = __expf(d - mn);
      s = s * sc + wq;
      ca = ca * sc + wq * eaA;
      cb = cb * sc + wq * e2A;
      m = mn;
    }
    if (j + 2 < 16) {
      const float* rn = eb + (size_t)(w + 4 * (j + 2)) * HH;
      eaA = ldnt4(rn + kq);
      e2A = ldnt4(rn + 256 + kq);
    }
    // process B (row w+4(j+1))
    {
      float d = eaB.x * h4a.x + eaB.y * h4a.y + eaB.z * h4a.z +
                eaB.w * h4a.w + e2B.x * h4b.x + e2B.y * h4b.y +
                e2B.z * h4b.z + e2B.w * h4b.w;
      d = wsum(d);
      if (lane == 0) sds[w + 4 * (j + 1)] = d;
      float mn = fmaxf(m, d);
      float sc = __expf(m - mn);
      float wq = __expf(d - mn);
      s = s * sc + wq;
      ca = ca * sc + wq * eaB;
      cb = cb * sc + wq * e2B;
      m = mn;
    }
    if (j + 3 < 16) {
      const float* rn = eb + (size_t)(w + 4 * (j + 3)) * HH;
      eaB = ldnt4(rn + kq);
      e2B = ldnt4(rn + 256 + kq);
    }
  }

  if (lane == 0) { sm[w] = m; ssum[w] = s; }
  ((f32x4*)(scx[w] + 0))[lane] = ca;
  ((f32x4*)(scx[w] + 256))[lane] = cb;
  __syncthreads();

  // flush scores (coalesced, once)
  if (tid < CH_ROWS) scores[b * LL + ch * CH_ROWS + tid] = sds[tid];

  float mb = fmaxf(fmaxf(sm[0], sm[1]), fmaxf(sm[2], sm[3]));
  if (tid == 0) {
    float sb = 0.f;
#pragma unroll
    for (int w2 = 0; w2 < 4; ++w2) sb += ssum[w2] * __expf(sm[w2] - mb);
    pm[b * NCH + ch] = mb;
    ps[b * NCH + ch] = sb;
  }
  for (int k = tid; k < 512; k += 256) {
    float v = 0.f;
#pragma unroll
    for (int w2 = 0; w2 < 4; ++w2) v += scx[w2][k] * __expf(sm[w2] - mb);
    pc[(size_t)(b * NCH + ch) * 512 + k] = v;
  }
}

// ---------------- K45: combine -> ctx + attn-weights output -------------
__global__ __launch_bounds__(256) void k45_ctx(
    const float* __restrict__ pm, const float* __restrict__ ps,
    const float* __restrict__ pc, const float* __restrict__ scores,
    float* __restrict__ cat, float* __restrict__ out2) {
  int b = blockIdx.x;
  int tid = threadIdx.x;
  float mb = -INFINITY;
#pragma unroll
  for (int ch = 0; ch < NCH; ++ch) mb = fmaxf(mb, pm[b * NCH + ch]);
  float e[NCH];
  float den = 0.f;
#pragma unroll
  for (int ch = 0; ch < NCH; ++ch) {
    e[ch] = __expf(pm[b * NCH + ch] - mb);
    den += ps[b * NCH + ch] * e[ch];
  }
  for (int k = tid; k < 512; k += 256) {
    float v = 0.f;
#pragma unroll
    for (int ch = 0; ch < NCH; ++ch)
      v += pc[(size_t)(b * NCH + ch) * 512 + k] * e[ch];
    cat[b * 1024 + 512 + k] = v / den;
  }
  float inv = 1.f / den;
  for (int t = tid; t < LL; t += 256) {
    out2[b * LL + t] = __expf(scores[b * LL + t] - mb) * inv;
  }
}

// ---------------- K6: concat GEMV -> bf16 (R11-proven) ------------------
__global__ __launch_bounds__(256) void k6_concat(
    const float* __restrict__ cat, const float* __restrict__ Wc,
    const float* __restrict__ bc, unsigned short* __restrict__ co_bf) {
  int lane = threadIdx.x & 63;
  int wid = blockIdx.x * 4 + (threadIdx.x >> 6);  // 0..4095
  int k = wid >> 3, bg = wid & 7;
  float wv[16];
  ld16(Wc + (size_t)k * 1024 + lane * 16, wv);
  float bk = bc[k];
  for (int b = bg * 8; b < bg * 8 + 8; ++b) {
    float cv[16];
    ld16(cat + b * 1024 + lane * 16, cv);
    float d = 0.f;
#pragma unroll
    for (int i = 0; i < 16; ++i) d += wv[i] * cv[i];
    d = wsum(d);
    if (lane == 0) co_bf[b * HH + k] = f2bf(tanhf(d + bk));
  }
}

// ---------------- K7: MFMA output GEMM + nontemporal Wo loads -----------
__global__ __launch_bounds__(256) void k7_out(
    const unsigned short* __restrict__ co_bf, const float* __restrict__ Wo,
    const float* __restrict__ bo, float* __restrict__ out0) {
  int t = threadIdx.x;
  int lane = t & 63, w = t >> 6;
  int v0 = blockIdx.x * 64 + w * 16;
  int l15 = lane & 15;
  int kbase = (lane >> 4) * 8;
  int vrow = v0 + l15;
  const float* wrow = Wo + (size_t)vrow * HH;

  f32x4 acc[4];
#pragma unroll
  for (int j = 0; j < 4; ++j) acc[j] = (f32x4){0.f, 0.f, 0.f, 0.f};

  for (int ks = 0; ks < HH; ks += 32) {
    int k = ks + kbase;
    f32x4 wa = ldnt4(wrow + k);
    f32x4 wb = ldnt4(wrow + k + 4);
    union { unsigned short u[8]; bf16x8 v; } B;
    B.u[0] = f2bf(wa.x); B.u[1] = f2bf(wa.y);
    B.u[2] = f2bf(wa.z); B.u[3] = f2bf(wa.w);
    B.u[4] = f2bf(wb.x); B.u[5] = f2bf(wb.y);
    B.u[6] = f2bf(wb.z); B.u[7] = f2bf(wb.w);
#pragma unroll
    for (int j = 0; j < 4; ++j) {
      bf16x8 A = *(const bf16x8*)(co_bf + (size_t)(j * 16 + l15) * HH + k);
      acc[j] = __builtin_amdgcn_mfma_f32_16x16x32_bf16(A, B.v, acc[j], 0, 0, 0);
    }
  }

  float bias = bo[vrow];
#pragma unroll
  for (int j = 0; j < 4; ++j) {
    int b0 = j * 16 + (lane >> 4) * 4;
#pragma unroll
    for (int r = 0; r < 4; ++r) {
      out0[(size_t)(b0 + r) * VV + vrow] = acc[j][r] + bias;
    }
  }
}

extern "C" void kernel_launch(void* const* d_in, const int* in_sizes, int n_in,
                              void* d_out, int out_size, void* d_ws,
                              size_t ws_size, hipStream_t stream) {
  const int* seq = (const int*)d_in[0];
  const float* last_hidden = (const float*)d_in[1];
  const float* enc = (const float*)d_in[2];
  // d_in[3] encoder_labels unused
  const float* feed = (const float*)d_in[4];
  const float* emb = (const float*)d_in[5];
  const float* Wih = (const float*)d_in[6];
  const float* Whh = (const float*)d_in[7];
  const float* bih = (const float*)d_in[8];
  const float* bhh = (const float*)d_in[9];
  const float* Wc = (const float*)d_in[10];
  const float* bc = (const float*)d_in[11];
  const float* Wo = (const float*)d_in[12];
  const float* bo = (const float*)d_in[13];

  float* out = (float*)d_out;
  float* out0 = out;            // B*V
  float* out1 = out + 2048000;  // B*H
  float* out2 = out + 2080768;  // B*L
  float* out3 = out + 2211840;  // B*H

  float* ws = (float*)d_ws;
  float* gi = ws;                  // 98304
  float* gh = gi + 98304;          // 98304
  float* cat = gh + 98304;         // 65536 (h_new | context)
  float* scores = cat + 65536;     // 131072
  float* pm = scores + 131072;     // 2048
  float* ps = pm + 2048;           // 2048
  float* pc = ps + 2048;           // 1048576 (B*NCH*512)
  unsigned short* co_bf = (unsigned short*)(pc + 1048576);  // 32768 u16

  hipLaunchKernelGGL(k1_gates, dim3(384), dim3(256), 0, stream,
                     seq, last_hidden, emb, Wih, Whh, bih, bhh, gi, gh);
  hipLaunchKernelGGL(k2_hnew, dim3(128), dim3(256), 0, stream,
                     gi, gh, last_hidden, feed, cat, out1, out3);
  hipLaunchKernelGGL(k3_attn, dim3(NCH, BB), dim3(256), 0, stream,
                     enc, cat, scores, pm, ps, pc);
  hipLaunchKernelGGL(k45_ctx, dim3(64), dim3(256), 0, stream,
                     pm, ps, pc, scores, cat, out2);
  hipLaunchKernelGGL(k6_concat, dim3(1024), dim3(256), 0, stream,
                     cat, Wc, bc, co_bf);
  hipLaunchKernelGGL(k7_out, dim3(500), dim3(256), 0, stream,
                     co_bf, Wo, bo, out0);
}